// Round 8
// baseline (551.435 us; speedup 1.0000x reference)
//
#include <hip/hip_runtime.h>
#include <cstddef>
#include <cstdint>

namespace {

constexpr int   kN = 512;
constexpr int   kB = 64;
constexpr float kAlpha = 0.8f;
constexpr float kBig  = 1e8f;
constexpr float kKexp = 144.26950408889634f;    // (1/gamma) * log2(e)
constexpr float kGLn2 = 0.006931471805599453f;  // gamma * ln(2)
constexpr float kWexp = 0.07213475204444817f;   // G * log2(e)

constexpr int W     = 4;     // waves per block (one per SIMD)
constexpr int DELTA = 16;    // global steps between block barriers
constexpr int LAM   = 80;    // per-wave lag = 64 + DELTA
constexpr int SMAX  = 574;   // last local step per wave (inclusive)
constexpr int GTOT  = 816;   // 51 supersteps cover g = 0..815

typedef __fp16 fp16x2 __attribute__((ext_vector_type(2)));

// lane u <- lane u-1 (lane 0 keeps own value); VALU-latency, replaces ds_bpermute
__device__ __forceinline__ float dpp_shr1(float x) {
    const int xi = __builtin_bit_cast(int, x);
    const int r  = __builtin_amdgcn_update_dpp(xi, xi, 0x138, 0xF, 0xF, false);
    return __builtin_bit_cast(float, r);
}

__global__ __launch_bounds__(256)
void dilate_wave4(const float* __restrict__ input,
                  const float* __restrict__ target,
                  uint32_t* __restrict__ Wg,
                  float* __restrict__ partials,
                  int b0)
{
    __shared__ float sx[kN];
    __shared__ float ringB[W][128];   // fwd: R row-boundary; bwd: cB boundary
    __shared__ float ringA[W][128];   // bwd: cA boundary
    __shared__ float sred[W];
    __shared__ float s_rnn;

    const int tid = (int)threadIdx.x;
    const int w = tid >> 6, u = tid & 63;
    const int wprev = (w > 0) ? (w - 1) : 0;
    const bool topw = (w == 0);
    const int b = b0 + (int)blockIdx.x;
    const int sOff = w * LAM;
    uint32_t* __restrict__ Wb = Wg + (size_t)blockIdx.x * (size_t)(kN * kN);

    float2 xv = reinterpret_cast<const float2*>(input + (size_t)b * kN)[tid];
    sx[2 * tid] = xv.x; sx[2 * tid + 1] = xv.y;
    float2 tv = reinterpret_cast<const float2*>(target + (size_t)b * kN)[tid];
    const float tk0 = tv.x, tk1 = tv.y;

    // normalized exponential time weights (rows 2tid, 2tid+1)
    float e0 = exp2f(kWexp * (float)(2 * tid));
    float e1 = exp2f(kWexp * (float)(2 * tid + 1));
    float es = e0 + e1;
    #pragma unroll
    for (int off = 32; off; off >>= 1) es += __shfl_xor(es, off);
    if (u == 0) sred[w] = es;
    __syncthreads();
    const float tot = sred[0] + sred[1] + sred[2] + sred[3];
    const float nrm = 512.0f / tot;
    const float wk0 = e0 * nrm, wk1 = e1 * nrm;

    // ================= forward soft-DTW =================
    float C0 = kBig, C1 = kBig;
    float aval = kBig, bval = kBig, prevRB = kBig;
    float rbNext = 0.0f;
    float xj = sx[0];

#define FWD_BODY(S, CHECKED)                                                \
    {                                                                       \
        const int c = (S) - u;                                              \
        bool valid = true;                                                  \
        int cn = c + 1;                                                     \
        if (CHECKED) {                                                      \
            valid = (c >= 0) & (c <= 511);                                  \
            cn = cn < 0 ? 0 : (cn > 511 ? 511 : cn);                        \
        }                                                                   \
        float Acur, Bcur;                                                   \
        if (u == 0) {                                                       \
            if (topw) { Bcur = kBig; Acur = ((S) == 0) ? 0.0f : kBig; }     \
            else      { Bcur = rB;   Acur = prevRB; }                       \
        } else { Acur = aval; Bcur = bval; }                                \
        prevRB = rB;                                                        \
        const float m0 = fminf(Bcur, fminf(Acur, C0));                      \
        const float eA0 = exp2f((m0 - Acur) * kKexp);                       \
        const float eB0 = exp2f((m0 - Bcur) * kKexp);                       \
        const float eC0 = exp2f((m0 - C0)   * kKexp);                       \
        const float ss0 = eA0 + eB0 + eC0;                                  \
        const float dx0 = tk0 - xj;                                         \
        float cur0 = fmaf(wk0 * dx0, dx0, m0 - kGLn2 * __log2f(ss0));       \
        const float ri0 = __builtin_amdgcn_rcpf(ss0);                       \
        fp16x2 hp0 = __builtin_amdgcn_cvt_pkrtz(eB0 * ri0, eC0 * ri0);      \
        if (CHECKED) cur0 = valid ? cur0 : kBig;                            \
        const float m1 = fminf(cur0, fminf(C0, C1));                        \
        const float eA1 = exp2f((m1 - C0)   * kKexp);                       \
        const float eB1 = exp2f((m1 - cur0) * kKexp);                       \
        const float eC1 = exp2f((m1 - C1)   * kKexp);                       \
        const float ss1 = eA1 + eB1 + eC1;                                  \
        const float dx1 = tk1 - xj;                                         \
        float cur1 = fmaf(wk1 * dx1, dx1, m1 - kGLn2 * __log2f(ss1));       \
        const float ri1 = __builtin_amdgcn_rcpf(ss1);                       \
        fp16x2 hp1 = __builtin_amdgcn_cvt_pkrtz(eB1 * ri1, eC1 * ri1);      \
        if (CHECKED) cur1 = valid ? cur1 : kBig;                            \
        C0 = cur0; C1 = cur1;                                               \
        if ((!(CHECKED)) || valid) {                                        \
            uint2 st;                                                       \
            st.x = __builtin_bit_cast(uint32_t, hp0);                       \
            st.y = __builtin_bit_cast(uint32_t, hp1);                       \
            *reinterpret_cast<uint2*>(Wb + (size_t)c * kN + 2 * tid) = st;  \
        }                                                                   \
        if (u == 63 && ((!(CHECKED)) || valid)) ringB[w][c & 127] = cur1;   \
        aval = bval;                                                        \
        bval = dpp_shr1(C1);                                                \
        xj = sx[cn];                                                        \
    }

    for (int ms = 0; ms < GTOT / DELTA; ++ms) {
        #pragma unroll
        for (int dg = 0; dg < DELTA; ++dg) {
            const int s = ms * DELTA + dg - sOff;
            if (s >= -1 && s <= SMAX) {
                const float rB = rbNext;
                rbNext = ringB[wprev][(s + 1) & 127];
                if (s >= 63 && s <= 510) { FWD_BODY(s, false) }
                else if (s >= 0)         { FWD_BODY(s, true) }
            }
        }
        __syncthreads();
    }
#undef FWD_BODY
    if (tid == 255) s_rnn = C1;    // R[512][512]
    __threadfence();
    __syncthreads();

    // ================= backward adjoint (primed coords) =================
    float cA0 = 0.0f, cC0 = 0.0f, cC1 = 0.0f;
    float shB = 0.0f, shA = 0.0f, shAp = 0.0f, savedBA = 0.0f;
    float rBBn = 0.0f, rBAn = 0.0f;
    float acc = 0.0f;
    const int rbase = 510 - 2 * tid;   // original row pair [rbase, rbase+1]

    auto addr = [&](int s) -> const uint2* {
        int jc = 511 - (s - u);        // original 0-based column
        jc = jc < 0 ? 0 : (jc > 511 ? 511 : jc);
        return reinterpret_cast<const uint2*>(Wb + (size_t)jc * kN + rbase);
    };
    uint2 P0 = *addr(0), P1 = *addr(1), P2 = *addr(2), P3 = *addr(3);
    uint2 P4 = *addr(4), P5 = *addr(5), P6 = *addr(6), P7 = *addr(7);

#define BS_BODY(S, P, CHECKED, SEED)                                        \
    {                                                                       \
        const int c = (S) - u;                                              \
        bool val_ = true;                                                   \
        if (CHECKED) val_ = (c >= 0) & (c <= 511);                          \
        float At0, Bt0;                                                     \
        if (u == 0) {                                                       \
            if (topw) { At0 = 0.0f; Bt0 = 0.0f; }                           \
            else      { At0 = savedBA; Bt0 = rBB; }                         \
        } else { At0 = shA; Bt0 = shB; }                                    \
        savedBA = rBA;                                                      \
        float E0 = At0 + Bt0 + cC0;                                         \
        if ((SEED) && topw && u == 0) E0 = 1.0f;                            \
        if (CHECKED) E0 = val_ ? E0 : 0.0f;                                 \
        const float d0 = (float)(c - 2 * tid);                              \
        acc = fmaf(E0 * d0, d0, acc);                                       \
        fp16x2 h0 = __builtin_bit_cast(fp16x2, P.y);                        \
        const float wb0 = (float)h0[0], wc0 = (float)h0[1];                 \
        const float nA0 = E0 * (1.0f - wb0 - wc0);                          \
        const float nB0 = E0 * wb0, nC0 = E0 * wc0;                         \
        float E1 = cA0 + nB0 + cC1;                                         \
        if (CHECKED) E1 = val_ ? E1 : 0.0f;                                 \
        const float d1 = d0 - 1.0f;                                         \
        acc = fmaf(E1 * d1, d1, acc);                                       \
        fp16x2 h1 = __builtin_bit_cast(fp16x2, P.x);                        \
        const float wb1 = (float)h1[0], wc1 = (float)h1[1];                 \
        const float nA1 = E1 * (1.0f - wb1 - wc1);                          \
        const float nB1 = E1 * wb1, nC1 = E1 * wc1;                         \
        cA0 = nA0; cC0 = nC0; cC1 = nC1;                                    \
        if (u == 63 && ((!(CHECKED)) || val_)) {                            \
            ringB[w][c & 127] = nB1;                                        \
            ringA[w][c & 127] = nA1;                                        \
        }                                                                   \
        shB = dpp_shr1(nB1);                                                \
        const float tA_ = dpp_shr1(nA1);                                    \
        shA = shAp; shAp = tA_;                                             \
        P = *addr((S) + 8);                                                 \
    }

#define BS(DG, P)                                                           \
    {                                                                       \
        const int s = ms * DELTA + (DG) - sOff;                             \
        if (s >= -1 && s <= SMAX) {                                         \
            const float rBB = rBBn, rBA = rBAn;                             \
            rBBn = ringB[wprev][(s + 1) & 127];                             \
            rBAn = ringA[wprev][(s + 1) & 127];                             \
            if (s >= 63 && s <= 511) { BS_BODY(s, P, false, false) }        \
            else if (s >= 0)         { BS_BODY(s, P, true, (s == 0)) }      \
        }                                                                   \
    }

    for (int ms = 0; ms < GTOT / DELTA; ++ms) {
        BS(0,  P0) BS(1,  P1) BS(2,  P2) BS(3,  P3)
        BS(4,  P4) BS(5,  P5) BS(6,  P6) BS(7,  P7)
        BS(8,  P0) BS(9,  P1) BS(10, P2) BS(11, P3)
        BS(12, P4) BS(13, P5) BS(14, P6) BS(15, P7)
        __syncthreads();
    }
#undef BS
#undef BS_BODY

    // ---- reduce temporal term, emit per-batch partial ----
    #pragma unroll
    for (int off = 32; off; off >>= 1) acc += __shfl_xor(acc, off);
    if (u == 0) sred[w] = acc;
    __syncthreads();
    if (tid == 0) {
        const float ts = sred[0] + sred[1] + sred[2] + sred[3];
        const float temporal = ts * (1.0f / (512.0f * 512.0f));
        partials[b] = (kAlpha * s_rnn + (1.0f - kAlpha) * temporal)
                    * (1.0f / (float)kB);
    }
}

__global__ void dilate_finalize(const float* __restrict__ partials,
                                float* __restrict__ out) {
    float v = partials[threadIdx.x];   // 64 threads = one wave
    #pragma unroll
    for (int off = 32; off > 0; off >>= 1) v += __shfl_down(v, off);
    if (threadIdx.x == 0) out[0] = v;
}

} // namespace

extern "C" void kernel_launch(void* const* d_in, const int* in_sizes, int n_in,
                              void* d_out, int out_size, void* d_ws, size_t ws_size,
                              hipStream_t stream) {
    (void)in_sizes; (void)n_in; (void)out_size;
    const float* input  = (const float*)d_in[0];
    const float* target = (const float*)d_in[1];
    float* out      = (float*)d_out;
    float* partials = (float*)d_ws;                          // kB floats
    uint32_t* Wbase = (uint32_t*)((char*)d_ws + 1024);       // weight slots

    const size_t per_batch = (size_t)kN * kN * sizeof(uint32_t);  // 1 MiB
    const size_t avail = (ws_size > 1024) ? (ws_size - 1024) : 0;
    int cap = (int)(avail / per_batch);
    if (cap > kB) cap = kB;
    if (cap < 1)  cap = 1;

    for (int b0 = 0; b0 < kB; b0 += cap) {
        const int nb = (kB - b0 < cap) ? (kB - b0) : cap;
        hipLaunchKernelGGL(dilate_wave4, dim3(nb), dim3(256), 0, stream,
                           input, target, Wbase, partials, b0);
    }
    hipLaunchKernelGGL(dilate_finalize, dim3(1), dim3(64), 0, stream,
                       partials, out);
}

// Round 9
// 518.397 us; speedup vs baseline: 1.0637x; 1.0637x over previous
//
#include <hip/hip_runtime.h>
#include <cstddef>
#include <cstdint>

namespace {

constexpr int   kN = 512;
constexpr int   kB = 64;
constexpr float kAlpha = 0.8f;
constexpr float kBig  = 1e8f;
constexpr float kKexp = 144.26950408889634f;    // (1/gamma) * log2(e)
constexpr float kGLn2 = 0.006931471805599453f;  // gamma * ln(2)
constexpr float kWexp = 0.07213475204444817f;   // G * log2(e)

constexpr int W     = 4;     // waves per block (one per SIMD)
constexpr int DELTA = 16;    // global steps between block barriers
constexpr int LAM   = 80;    // per-wave lag = 64 + DELTA
constexpr int SMAX  = 574;   // last local step per wave (inclusive)
constexpr int GTOT  = 816;   // 51 supersteps cover g = 0..815

typedef __fp16 fp16x2 __attribute__((ext_vector_type(2)));

// Diagonal-major weight storage: one 64-entry uint2 record per (wave, step).
// Fwd wave w, local step s, lane u writes record [(3-w)*576 + (574-s)],
// entry (63-u). Bwd wave w', step s', lane u' reads record [w'*576 + s'],
// entry u'. Both sides are contiguous 512 B per wave-step (coalesced).
__global__ __launch_bounds__(256)
void dilate_wave4(const float* __restrict__ input,
                  const float* __restrict__ target,
                  uint2* __restrict__ Wg,
                  float* __restrict__ partials,
                  int b0)
{
    __shared__ float sx[kN];
    __shared__ float ringB[W][128];   // fwd: R row-boundary; bwd: cB boundary
    __shared__ float ringA[W][128];   // bwd: cA boundary
    __shared__ float sred[W];
    __shared__ float s_rnn;

    const int tid = (int)threadIdx.x;
    const int w = tid >> 6, u = tid & 63;
    const int wprev = (w > 0) ? (w - 1) : 0;
    const bool topw = (w == 0);
    const int b = b0 + (int)blockIdx.x;
    const int sOff = w * LAM;
    uint2* __restrict__ Wd = Wg + (size_t)blockIdx.x * (size_t)(W * 576 * 64);

    float2 xv = reinterpret_cast<const float2*>(input + (size_t)b * kN)[tid];
    sx[2 * tid] = xv.x; sx[2 * tid + 1] = xv.y;
    float2 tv = reinterpret_cast<const float2*>(target + (size_t)b * kN)[tid];
    const float tk0 = tv.x, tk1 = tv.y;

    // normalized exponential time weights (rows 2tid, 2tid+1)
    float e0 = exp2f(kWexp * (float)(2 * tid));
    float e1 = exp2f(kWexp * (float)(2 * tid + 1));
    float es = e0 + e1;
    #pragma unroll
    for (int off = 32; off; off >>= 1) es += __shfl_xor(es, off);
    if (u == 0) sred[w] = es;
    __syncthreads();
    const float tot = sred[0] + sred[1] + sred[2] + sred[3];
    const float nrm = 512.0f / tot;
    const float wk0 = e0 * nrm, wk1 = e1 * nrm;

    // ================= forward soft-DTW =================
    float C0 = kBig, C1 = kBig;
    float aval = kBig, bval = kBig, prevRB = kBig;
    float xj = sx[0];

    for (int m = 0; m < GTOT / DELTA; ++m) {
        for (int dg = 0; dg < DELTA; ++dg) {
            const int s = m * DELTA + dg - sOff;
            if (s >= 0 && s <= SMAX) {
                const int c = s - u;
                const bool valid = (c >= 0) & (c <= 511);
                const float rB = ringB[wprev][s & 127];
                float Acur, Bcur;
                if (u == 0) {
                    if (topw) { Bcur = kBig; Acur = (s == 0) ? 0.0f : kBig; }
                    else      { Bcur = rB;   Acur = prevRB; }
                } else { Acur = aval; Bcur = bval; }
                prevRB = rB;
                // cell 0 (row 2tid)
                const float m0 = fminf(Bcur, fminf(Acur, C0));
                const float eA0 = exp2f((m0 - Acur) * kKexp);
                const float eB0 = exp2f((m0 - Bcur) * kKexp);
                const float eC0 = exp2f((m0 - C0)   * kKexp);
                const float ss0 = eA0 + eB0 + eC0;
                const float dx0 = tk0 - xj;
                float cur0 = fmaf(wk0 * dx0, dx0, m0 - kGLn2 * __log2f(ss0));
                const float ri0 = __builtin_amdgcn_rcpf(ss0);
                fp16x2 hp0 = __builtin_amdgcn_cvt_pkrtz(eB0 * ri0, eC0 * ri0);
                cur0 = valid ? cur0 : kBig;
                // cell 1 (row 2tid+1)
                const float m1 = fminf(cur0, fminf(C0, C1));
                const float eA1 = exp2f((m1 - C0)   * kKexp);
                const float eB1 = exp2f((m1 - cur0) * kKexp);
                const float eC1 = exp2f((m1 - C1)   * kKexp);
                const float ss1 = eA1 + eB1 + eC1;
                const float dx1 = tk1 - xj;
                float cur1 = fmaf(wk1 * dx1, dx1, m1 - kGLn2 * __log2f(ss1));
                const float ri1 = __builtin_amdgcn_rcpf(ss1);
                fp16x2 hp1 = __builtin_amdgcn_cvt_pkrtz(eB1 * ri1, eC1 * ri1);
                cur1 = valid ? cur1 : kBig;
                C0 = cur0; C1 = cur1;
                // coalesced record write (unconditional; invalid lanes finite)
                {
                    uint2 st;
                    st.x = __builtin_bit_cast(uint32_t, hp0);
                    st.y = __builtin_bit_cast(uint32_t, hp1);
                    Wd[((size_t)(3 - w) * 576 + (574 - s)) * 64 + (63 - u)] = st;
                }
                if (u == 63 && valid) ringB[w][c & 127] = cur1;
                aval = bval;
                bval = __shfl_up(C1, 1);
                int cn = c + 1; cn = cn < 0 ? 0 : (cn > 511 ? 511 : cn);
                xj = sx[cn];
            }
        }
        __syncthreads();
    }
    if (tid == 255) s_rnn = C1;    // R[512][512]
    __threadfence();
    __syncthreads();

    // ================= backward adjoint (primed coords) =================
    float cA0 = 0.0f, cC0 = 0.0f, cC1 = 0.0f;
    float shB = 0.0f, shA = 0.0f, shAp = 0.0f, savedBA = 0.0f;
    float acc = 0.0f;

    auto addr = [&](int s) -> const uint2* {
        int sc = s > 574 ? 574 : (s < 0 ? 0 : s);
        return Wd + ((size_t)w * 576 + sc) * 64 + u;
    };
    uint2 P0 = *addr(0), P1 = *addr(1), P2 = *addr(2), P3 = *addr(3);
    uint2 P4 = *addr(4), P5 = *addr(5), P6 = *addr(6), P7 = *addr(7);

#define BS(DG, P)                                                           \
    {                                                                       \
        const int s = m * DELTA + (DG) - sOff;                              \
        if (s >= 0 && s <= SMAX) {                                          \
            const int c = s - u;                                            \
            const bool valid = (c >= 0) & (c <= 511);                       \
            const float rBB = ringB[wprev][s & 127];                        \
            const float rBA = ringA[wprev][s & 127];                        \
            float At0, Bt0;                                                 \
            if (u == 0) {                                                   \
                if (topw) { At0 = 0.0f; Bt0 = 0.0f; }                       \
                else      { At0 = savedBA; Bt0 = rBB; }                     \
            } else { At0 = shA; Bt0 = shB; }                                \
            savedBA = rBA;                                                  \
            float E0 = At0 + Bt0 + cC0;                                     \
            if (topw && u == 0 && s == 0) E0 = 1.0f;   /* seed E[N,N] */    \
            E0 = valid ? E0 : 0.0f;                                         \
            const float d0 = (float)(c - 2 * tid);                          \
            acc = fmaf(E0 * d0, d0, acc);                                   \
            fp16x2 h0 = __builtin_bit_cast(fp16x2, P.y);                    \
            const float wb0 = (float)h0[0], wc0 = (float)h0[1];             \
            const float nA0 = E0 * (1.0f - wb0 - wc0);                      \
            const float nB0 = E0 * wb0, nC0 = E0 * wc0;                     \
            float E1 = cA0 + nB0 + cC1;                                     \
            E1 = valid ? E1 : 0.0f;                                         \
            const float d1 = d0 - 1.0f;                                     \
            acc = fmaf(E1 * d1, d1, acc);                                   \
            fp16x2 h1 = __builtin_bit_cast(fp16x2, P.x);                    \
            const float wb1 = (float)h1[0], wc1 = (float)h1[1];             \
            const float nA1 = E1 * (1.0f - wb1 - wc1);                      \
            const float nB1 = E1 * wb1, nC1 = E1 * wc1;                     \
            cA0 = nA0; cC0 = nC0; cC1 = nC1;                                \
            if (u == 63 && valid) {                                         \
                ringB[w][c & 127] = nB1;                                    \
                ringA[w][c & 127] = nA1;                                    \
            }                                                               \
            const float tB = __shfl_up(nB1, 1);                             \
            const float tA = __shfl_up(nA1, 1);                             \
            shB = tB; shA = shAp; shAp = tA;                                \
            P = *addr(s + 8);                                               \
        }                                                                   \
    }

    for (int m = 0; m < GTOT / DELTA; ++m) {
        BS(0,  P0) BS(1,  P1) BS(2,  P2) BS(3,  P3)
        BS(4,  P4) BS(5,  P5) BS(6,  P6) BS(7,  P7)
        BS(8,  P0) BS(9,  P1) BS(10, P2) BS(11, P3)
        BS(12, P4) BS(13, P5) BS(14, P6) BS(15, P7)
        __syncthreads();
    }
#undef BS

    // ---- reduce temporal term, emit per-batch partial ----
    #pragma unroll
    for (int off = 32; off; off >>= 1) acc += __shfl_xor(acc, off);
    if (u == 0) sred[w] = acc;
    __syncthreads();
    if (tid == 0) {
        const float ts = sred[0] + sred[1] + sred[2] + sred[3];
        const float temporal = ts * (1.0f / (512.0f * 512.0f));
        partials[b] = (kAlpha * s_rnn + (1.0f - kAlpha) * temporal)
                    * (1.0f / (float)kB);
    }
}

__global__ void dilate_finalize(const float* __restrict__ partials,
                                float* __restrict__ out) {
    float v = partials[threadIdx.x];   // 64 threads = one wave
    #pragma unroll
    for (int off = 32; off > 0; off >>= 1) v += __shfl_down(v, off);
    if (threadIdx.x == 0) out[0] = v;
}

} // namespace

extern "C" void kernel_launch(void* const* d_in, const int* in_sizes, int n_in,
                              void* d_out, int out_size, void* d_ws, size_t ws_size,
                              hipStream_t stream) {
    (void)in_sizes; (void)n_in; (void)out_size;
    const float* input  = (const float*)d_in[0];
    const float* target = (const float*)d_in[1];
    float* out      = (float*)d_out;
    float* partials = (float*)d_ws;                        // kB floats
    uint2* Wbase    = (uint2*)((char*)d_ws + 1024);        // weight records

    const size_t per_batch = (size_t)W * 576 * 64 * sizeof(uint2);  // ~1.18 MiB
    const size_t avail = (ws_size > 1024) ? (ws_size - 1024) : 0;
    int cap = (int)(avail / per_batch);
    if (cap > kB) cap = kB;
    if (cap < 1)  cap = 1;

    for (int b0 = 0; b0 < kB; b0 += cap) {
        const int nb = (kB - b0 < cap) ? (kB - b0) : cap;
        hipLaunchKernelGGL(dilate_wave4, dim3(nb), dim3(256), 0, stream,
                           input, target, Wbase, partials, b0);
    }
    hipLaunchKernelGGL(dilate_finalize, dim3(1), dim3(64), 0, stream,
                       partials, out);
}

// Round 10
// 264.242 us; speedup vs baseline: 2.0869x; 1.9618x over previous
//
#include <hip/hip_runtime.h>
#include <cstddef>
#include <cstdint>

namespace {

constexpr int   kN = 512;
constexpr int   kB = 64;
constexpr float kAlpha = 0.8f;
constexpr float kBig  = 1e8f;
constexpr float kKexp = 144.26950408889634f;    // (1/gamma) * log2(e)
constexpr float kGLn2 = 0.006931471805599453f;  // gamma * ln(2)
constexpr float kWexp = 0.07213475204444817f;   // G * log2(e)

constexpr int W     = 4;     // waves per block (one per SIMD)
constexpr int DELTA = 16;    // global steps between block barriers
constexpr int LAM   = 80;    // per-wave lag = 64 + DELTA
constexpr int SMAX  = 574;   // last local step per wave (inclusive)
constexpr int GTOT  = 816;   // 51 supersteps cover g = 0..814

// Single forward pass computing (R, Rdot) where Rdot = JVP of soft-DTW in
// direction Omega_ij = (i-j)^2. loss_temporal = Rdot[N,N]/N^2 — no backward
// pass, no weight storage, no global scratch traffic.
// 4 staggered waves per batch; wave w owns rows [128w,128w+128); lane u owns
// rows 2tid,2tid+1 (1-based i=2tid+1,2tid+2). Step s: column c=s-u.
__global__ __launch_bounds__(256)
void dilate_jvp(const float* __restrict__ input,
                const float* __restrict__ target,
                float* __restrict__ partials,
                int b0)
{
    __shared__ float sx[kN];
    __shared__ float ringR[W][128];   // row-boundary R
    __shared__ float ringD[W][128];   // row-boundary Rdot
    __shared__ float sred[W];

    const int tid = (int)threadIdx.x;
    const int w = tid >> 6, u = tid & 63;
    const int wprev = (w > 0) ? (w - 1) : 0;
    const bool topw = (w == 0);
    const int b = b0 + (int)blockIdx.x;
    const int sOff = w * LAM;

    float2 xv = reinterpret_cast<const float2*>(input + (size_t)b * kN)[tid];
    sx[2 * tid] = xv.x; sx[2 * tid + 1] = xv.y;
    float2 tv = reinterpret_cast<const float2*>(target + (size_t)b * kN)[tid];
    const float tk0 = tv.x, tk1 = tv.y;

    // normalized exponential time weights (rows 2tid, 2tid+1)
    float e0 = exp2f(kWexp * (float)(2 * tid));
    float e1 = exp2f(kWexp * (float)(2 * tid + 1));
    float es = e0 + e1;
    #pragma unroll
    for (int off = 32; off; off >>= 1) es += __shfl_xor(es, off);
    if (u == 0) sred[w] = es;
    __syncthreads();
    const float tot = sred[0] + sred[1] + sred[2] + sred[3];
    const float nrm = 512.0f / tot;
    const float wk0 = e0 * nrm, wk1 = e1 * nrm;

    // ================= forward soft-DTW with dual (JVP) =================
    float C0 = kBig, C1 = kBig, C0d = 0.0f, C1d = 0.0f;
    float aval = kBig, bval = kBig, avald = 0.0f, bvald = 0.0f;
    float prevRB = kBig, prevRBd = 0.0f;
    float xj = sx[0];

    for (int m = 0; m < GTOT / DELTA; ++m) {
        for (int dg = 0; dg < DELTA; ++dg) {
            const int s = m * DELTA + dg - sOff;
            if (s >= 0 && s <= SMAX) {
                const int c = s - u;
                const bool valid = (c >= 0) & (c <= 511);
                const float rB  = ringR[wprev][s & 127];
                const float rBd = ringD[wprev][s & 127];
                float Acur, Bcur, Ad, Bd;
                if (u == 0) {
                    if (topw) { Bcur = kBig; Bd = 0.0f;
                                Acur = (s == 0) ? 0.0f : kBig; Ad = 0.0f; }
                    else      { Bcur = rB; Bd = rBd;
                                Acur = prevRB; Ad = prevRBd; }
                } else { Acur = aval; Ad = avald; Bcur = bval; Bd = bvald; }
                prevRB = rB; prevRBd = rBd;
                const float fd = (float)(2 * tid + u - s);   // i - j for cell 0
                // ---- cell 0 (row 2tid+1, 1-based) ----
                const float m0  = fminf(Bcur, fminf(Acur, C0));
                const float mk0 = m0 * kKexp;
                const float eA0 = exp2f(fmaf(-kKexp, Acur, mk0));
                const float eB0 = exp2f(fmaf(-kKexp, Bcur, mk0));
                const float eC0 = exp2f(fmaf(-kKexp, C0,   mk0));
                const float ss0 = eA0 + eB0 + eC0;
                const float ri0 = __builtin_amdgcn_rcpf(ss0);
                const float dx0 = tk0 - xj;
                float cur0 = fmaf(wk0 * dx0, dx0, m0 - kGLn2 * __log2f(ss0));
                const float sd0 = fmaf(eA0, Ad, fmaf(eB0, Bd, eC0 * C0d));
                float cur0d = fmaf(ri0, sd0, fd * fd);
                cur0  = valid ? cur0  : kBig;
                cur0d = valid ? cur0d : 0.0f;
                // ---- cell 1 (row 2tid+2): A=old C0, B=cur0, C=C1 ----
                const float m1  = fminf(cur0, fminf(C0, C1));
                const float mk1 = m1 * kKexp;
                const float eA1 = exp2f(fmaf(-kKexp, C0,   mk1));
                const float eB1 = exp2f(fmaf(-kKexp, cur0, mk1));
                const float eC1 = exp2f(fmaf(-kKexp, C1,   mk1));
                const float ss1 = eA1 + eB1 + eC1;
                const float ri1 = __builtin_amdgcn_rcpf(ss1);
                const float dx1 = tk1 - xj;
                float cur1 = fmaf(wk1 * dx1, dx1, m1 - kGLn2 * __log2f(ss1));
                const float fd1 = fd + 1.0f;
                const float sd1 = fmaf(eA1, C0d, fmaf(eB1, cur0d, eC1 * C1d));
                float cur1d = fmaf(ri1, sd1, fd1 * fd1);
                cur1  = valid ? cur1  : kBig;
                cur1d = valid ? cur1d : 0.0f;
                C0 = cur0; C0d = cur0d; C1 = cur1; C1d = cur1d;
                if (u == 63 && valid) {
                    ringR[w][c & 127] = cur1;
                    ringD[w][c & 127] = cur1d;
                }
                aval = bval; avald = bvald;
                bval  = __shfl_up(C1, 1);
                bvald = __shfl_up(C1d, 1);
                int cn = c + 1; cn = cn < 0 ? 0 : (cn > 511 ? 511 : cn);
                xj = sx[cn];
            }
        }
        __syncthreads();
    }

    // tid 255 (wave 3, lane 63) holds R[512][512] and Rdot[512][512]
    if (tid == 255) {
        const float temporal = C1d * (1.0f / (512.0f * 512.0f));
        partials[b] = (kAlpha * C1 + (1.0f - kAlpha) * temporal)
                    * (1.0f / (float)kB);
    }
}

__global__ void dilate_finalize(const float* __restrict__ partials,
                                float* __restrict__ out) {
    float v = partials[threadIdx.x];   // 64 threads = one wave
    #pragma unroll
    for (int off = 32; off > 0; off >>= 1) v += __shfl_down(v, off);
    if (threadIdx.x == 0) out[0] = v;
}

} // namespace

extern "C" void kernel_launch(void* const* d_in, const int* in_sizes, int n_in,
                              void* d_out, int out_size, void* d_ws, size_t ws_size,
                              hipStream_t stream) {
    (void)in_sizes; (void)n_in; (void)out_size; (void)ws_size;
    const float* input  = (const float*)d_in[0];
    const float* target = (const float*)d_in[1];
    float* out      = (float*)d_out;
    float* partials = (float*)d_ws;    // kB floats

    hipLaunchKernelGGL(dilate_jvp, dim3(kB), dim3(256), 0, stream,
                       input, target, partials, 0);
    hipLaunchKernelGGL(dilate_finalize, dim3(1), dim3(64), 0, stream,
                       partials, out);
}